// Round 7
// baseline (211.012 us; speedup 1.0000x reference)
//
#include <hip/hip_runtime.h>

using u16 = unsigned short;
typedef float  f32x4  __attribute__((ext_vector_type(4)));
typedef float  f32x16 __attribute__((ext_vector_type(16)));
typedef __bf16 bf8_t  __attribute__((ext_vector_type(8)));
typedef u16    u16x4  __attribute__((ext_vector_type(4)));
typedef unsigned int u32x2 __attribute__((ext_vector_type(2)));

#define NB 2
#define NH 16
#define NT 2048
#define ND 32
#define NC 512
#define QK_SCALE 0.17677669529663687f   // 1/sqrt(32)
#define LOG2E    1.4426950408889634f

__device__ __forceinline__ u16 f2bf(float f) {
  unsigned int u = __float_as_uint(f);
  u += 0x7fffu + ((u >> 16) & 1u);      // RNE
  return (u16)(u >> 16);
}

__device__ __forceinline__ unsigned int cvt_pk_bf16(float a, float b) {
  unsigned int r;
  asm("v_cvt_pk_bf16_f32 %0, %1, %2" : "=v"(r) : "v"(a), "v"(b));
  return r;                             // lo16 = bf16(a), hi16 = bf16(b)
}

__device__ __forceinline__ f32x4 mfma16(bf8_t a, bf8_t b, f32x4 c) {
  return __builtin_amdgcn_mfma_f32_16x16x32_bf16(a, b, c, 0, 0, 0);
}
__device__ __forceinline__ f32x16 mfma32(bf8_t a, bf8_t b, f32x16 c) {
  return __builtin_amdgcn_mfma_f32_32x32x16_bf16(a, b, c, 0, 0, 0);
}

// ---------------------------------------------------------------------------
// Kernel 1: prep. z<6: q/k/v (B,C,T) f32 -> Xt (B,T,C) bf16 (LDS transpose).
// z==6: weights -> bf16 (Wq pre-scaled by log2e/sqrt(D)); block 0 also emits
// maskf (0/1), maskb (0/-1e30) and the mask chunk of d_out.
// ---------------------------------------------------------------------------
__global__ __launch_bounds__(256) void prep_kernel(
    const float* __restrict__ q, const float* __restrict__ k,
    const float* __restrict__ v, u16* __restrict__ Xt,
    const float* __restrict__ Wq, const float* __restrict__ Wk,
    const float* __restrict__ Wv, const float* __restrict__ Wp,
    const void* __restrict__ mraw,
    u16* __restrict__ Wc, float* __restrict__ maskf, float* __restrict__ maskb,
    float* __restrict__ outtail) {
  int z = blockIdx.z;
  int tx = threadIdx.x, ty = threadIdx.y;
  if (z == 6) {                          // weight conversion (+ mask on block 0)
    int bid = blockIdx.y * 64 + blockIdx.x;      // 0..1023
    int tid = ty * 32 + tx;
    int idx = (bid * 256 + tid) * 4;
    int m   = idx >> 18;                 // 262144 elements per matrix
    int off = idx & 262143;
    const float* W = (m == 0) ? Wq : (m == 1) ? Wk : (m == 2) ? Wv : Wp;
    float s = (m == 0) ? (QK_SCALE * LOG2E) : 1.0f;
    f32x4 wv = *(const f32x4*)(W + off);
    u16x4 pk;
    #pragma unroll
    for (int r = 0; r < 4; ++r) pk[r] = f2bf(wv[r] * s);
    *(u16x4*)(Wc + (size_t)m * (NC * NC) + off) = pk;
    if (bid == 0) {
      unsigned int w0 = *(const unsigned int*)mraw;   // bool-bytes vs int32
      bool intlay = (w0 == 1u);
      #pragma unroll
      for (int kk = 0; kk < 16; ++kk) {
        int j = tid + kk * 256;          // 0..4095 = NB*NT
        float mv;
        if (intlay) mv = ((const int*)mraw)[j] ? 1.0f : 0.0f;
        else        mv = ((const unsigned char*)mraw)[j] ? 1.0f : 0.0f;
        maskf[j]   = mv;
        maskb[j]   = (mv - 1.0f) * 1e30f;
        outtail[j] = mv;
      }
    }
    return;
  }
  __shared__ float tile[32][33];
  int m = z >> 1, b = z & 1;
  const float* src = (m == 0) ? q : (m == 1) ? k : v;
  int t0 = blockIdx.x * 32, c0 = blockIdx.y * 32;
  #pragma unroll
  for (int j = 0; j < 4; ++j)
    tile[ty + j * 8][tx] = src[(size_t)(b * NC + c0 + ty + j * 8) * NT + t0 + tx];
  __syncthreads();
  u16* dst = Xt + (size_t)m * (NB * NT * NC);
  #pragma unroll
  for (int j = 0; j < 4; ++j)
    dst[((size_t)b * NT + t0 + ty + j * 8) * NC + c0 + tx] = f2bf(tile[tx][ty + j * 8]);
}

// ---------------------------------------------------------------------------
// Kernel 2: 3 input projections (R2-proven M=64 x N=128 tile, direct frags).
// grid (8, 32, 3).  z: 0=Q -> (B,H,T,D) scaled; 1=K -> (B,H,T,D);
// 2=V -> (B,C,T) masked.
// ---------------------------------------------------------------------------
__global__ __launch_bounds__(256) void proj_kernel(
    const u16* __restrict__ Wc, const u16* __restrict__ Xt,
    const float* __restrict__ bq, const float* __restrict__ bk, const float* __restrict__ bv,
    u16* __restrict__ Qw, u16* __restrict__ Kw, u16* __restrict__ Vw,
    const float* __restrict__ maskf) {
  int z = blockIdx.z;
  const u16* W = Wc + (size_t)z * (NC * NC);
  const float* bias = (z == 0) ? bq : (z == 1) ? bk : bv;
  int tid = threadIdx.x, wid = tid >> 6, lane = tid & 63;
  int lq = lane & 15, g = lane >> 4;
  int om0 = blockIdx.x * 64;
  int b   = blockIdx.y >> 4;
  int t0  = (blockIdx.y & 15) * 128 + wid * 32;
  const u16* Xb = Xt + (size_t)z * (NB * NT * NC) + (size_t)b * NT * NC;

  const f32x4 zero = {0.f, 0.f, 0.f, 0.f};
  f32x4 acc[4][2];
  #pragma unroll
  for (int mt = 0; mt < 4; ++mt)
    #pragma unroll
    for (int nt = 0; nt < 2; ++nt) acc[mt][nt] = zero;

  for (int ks = 0; ks < 16; ++ks) {       // K = 512, BK = 32
    bf8_t af[4], bfr[2];
    #pragma unroll
    for (int mt = 0; mt < 4; ++mt)
      af[mt] = *(const bf8_t*)(W + (size_t)(om0 + mt * 16 + lq) * NC + ks * 32 + 8 * g);
    #pragma unroll
    for (int nt = 0; nt < 2; ++nt)
      bfr[nt] = *(const bf8_t*)(Xb + (size_t)(t0 + nt * 16 + lq) * NC + ks * 32 + 8 * g);
    #pragma unroll
    for (int mt = 0; mt < 4; ++mt)
      #pragma unroll
      for (int nt = 0; nt < 2; ++nt)
        acc[mt][nt] = mfma16(af[mt], bfr[nt], acc[mt][nt]);
  }

  float sc = (z == 0) ? (QK_SCALE * LOG2E) : 1.0f;
  #pragma unroll
  for (int mt = 0; mt < 4; ++mt) {
    int ob = om0 + mt * 16 + 4 * g;       // 4 consecutive output channels (regs)
    float b4[4];
    #pragma unroll
    for (int r = 0; r < 4; ++r) b4[r] = bias[ob + r] * sc;
    #pragma unroll
    for (int nt = 0; nt < 2; ++nt) {
      int t = t0 + nt * 16 + lq;
      if (z < 2) {
        u16x4 pk;
        #pragma unroll
        for (int r = 0; r < 4; ++r) pk[r] = f2bf(acc[mt][nt][r] + b4[r]);
        u16* dst = (z == 0) ? Qw : Kw;
        *(u16x4*)(dst + ((size_t)(b * NH + (ob >> 5)) * NT + t) * ND + (ob & 31)) = pk;
      } else {
        float mv = maskf[b * NT + t];     // vm = vh * mask
        #pragma unroll
        for (int r = 0; r < 4; ++r)
          Vw[(size_t)(b * NC + ob + r) * NT + t] = f2bf((acc[mt][nt][r] + b4[r]) * mv);
      }
    }
  }
}

// ---------------------------------------------------------------------------
// Kernel 3: flash attention on 32x32x16 MFMA, fully in-register P.
// One wave owns 32 q-rows x full KV. S^T tile 128tk x 32tq = 4 f32x16.
// Lane holds entire P-row for tq=lane&31 (tk-halves split with lane+32):
// softmax reduce = tree + 1 shfl_xor(32); P -> PV B-frags via
// 4x cvt_pk + 2x v_permlane32_swap per 16-tk fragment. NO LDS, NO barriers.
// Mask bias rides the QK^T MFMA C-in. Grid (16,32) = 512 blocks.
// ---------------------------------------------------------------------------
__global__ __launch_bounds__(256) void attn_kernel(
    const u16* __restrict__ Qw, const u16* __restrict__ Kw, const u16* __restrict__ Vw,
    u16* __restrict__ Ow, const float* __restrict__ maskb) {
  int tid = threadIdx.x, wid = tid >> 6, lane = tid & 63;
  int lr = lane & 31, hh = lane >> 5;
  int bh = blockIdx.y, b = bh >> 4, hd = bh & 15;
  int q0 = blockIdx.x * 128 + wid * 32;
  const u16* Qb = Qw + (size_t)bh * NT * ND;
  const u16* Kb = Kw + (size_t)bh * NT * ND;
  const u16* Vb = Vw + (size_t)(b * NC + hd * ND + lr) * NT;   // row d = lr
  const float* mbp = maskb + b * NT;

  const u16* Qrow = Qb + (size_t)(q0 + lr) * ND + 8 * hh;
  bf8_t qf0 = *(const bf8_t*)(Qrow);
  bf8_t qf1 = *(const bf8_t*)(Qrow + 16);

  f32x16 acc;
  #pragma unroll
  for (int r = 0; r < 16; ++r) acc[r] = 0.f;
  float lsum = 0.f, mrun = 0.f;

  for (int kt = 0; kt < 16; ++kt) {
    int tkb = kt * 128;
    // S^T = K @ Q^T + mask_bias (C-in; C/D row = tk_local, col = tq)
    f32x16 st[4];
    #pragma unroll
    for (int t = 0; t < 4; ++t) {
      const float* bb = mbp + tkb + 32 * t + 4 * hh;
      union { f32x16 v; f32x4 q[4]; } bias;
      bias.q[0] = *(const f32x4*)(bb);
      bias.q[1] = *(const f32x4*)(bb + 8);
      bias.q[2] = *(const f32x4*)(bb + 16);
      bias.q[3] = *(const f32x4*)(bb + 24);
      const u16* Kt = Kb + (size_t)(tkb + 32 * t + lr) * ND + 8 * hh;
      bf8_t k0 = *(const bf8_t*)(Kt);
      bf8_t k1 = *(const bf8_t*)(Kt + 16);
      st[t] = mfma32(k0, qf0, bias.v);
      st[t] = mfma32(k1, qf1, st[t]);
    }
    // V fragments: issue now, consumed after softmax (latency hides under exp)
    bf8_t vf[4][2];
    #pragma unroll
    for (int t = 0; t < 4; ++t)
      #pragma unroll
      for (int kh = 0; kh < 2; ++kh)
        vf[t][kh] = *(const bf8_t*)(Vb + tkb + 32 * t + 16 * kh + 8 * hh);

    // ---- max reduce (ILP tree; lane pair l/l+32 share tq) ----
    float m8[8];
    #pragma unroll
    for (int r = 0; r < 8; ++r)
      m8[r] = fmaxf(fmaxf(st[0][r], st[0][r + 8]), fmaxf(st[1][r], st[1][r + 8]));
    #pragma unroll
    for (int r = 0; r < 8; ++r)
      m8[r] = fmaxf(m8[r], fmaxf(fmaxf(st[2][r], st[2][r + 8]),
                                 fmaxf(st[3][r], st[3][r + 8])));
    float tm = fmaxf(fmaxf(fmaxf(m8[0], m8[1]), fmaxf(m8[2], m8[3])),
                     fmaxf(fmaxf(m8[4], m8[5]), fmaxf(m8[6], m8[7])));
    tm = fmaxf(tm, __shfl_xor(tm, 32));
    if (__any(tm > mrun + 2.0f)) {        // defer-max: rescale rarely
      float mnew = fmaxf(mrun, tm);
      float al = __builtin_amdgcn_exp2f(mrun - mnew);
      mrun = mnew;
      #pragma unroll
      for (int r = 0; r < 16; ++r) acc[r] *= al;
      lsum *= al;
    }
    float nm = -mrun;
    // ---- exp2 (scores already in log2 domain) ----
    #pragma unroll
    for (int t = 0; t < 4; ++t)
      #pragma unroll
      for (int r = 0; r < 16; ++r)
        st[t][r] = __builtin_amdgcn_exp2f(st[t][r] + nm);
    // ---- row sum (ILP tree + 1 shfl) ----
    float s8[8];
    #pragma unroll
    for (int r = 0; r < 8; ++r)
      s8[r] = (st[0][r] + st[0][r + 8]) + (st[1][r] + st[1][r + 8])
            + (st[2][r] + st[2][r + 8]) + (st[3][r] + st[3][r + 8]);
    float rs = ((s8[0] + s8[1]) + (s8[2] + s8[3]))
             + ((s8[4] + s8[5]) + (s8[6] + s8[7]));
    rs += __shfl_xor(rs, 32);
    lsum += rs;
    // ---- P -> bf16 B-frags in-register, PV MFMA ----
    // rows per lane: (reg&3)+8*(reg>>2)+4*hh; B-frag needs k=8*hh+j.
    // swap(dst=b,src=a): a' = {a_lo,b_lo} (=w0/w1), b' = {a_hi,b_hi} (=w2/w3).
    #pragma unroll
    for (int t = 0; t < 4; ++t) {
      #pragma unroll
      for (int kh = 0; kh < 2; ++kh) {
        int r0 = kh * 8;
        unsigned a0 = cvt_pk_bf16(st[t][r0 + 0], st[t][r0 + 1]);
        unsigned a1 = cvt_pk_bf16(st[t][r0 + 2], st[t][r0 + 3]);
        unsigned b0 = cvt_pk_bf16(st[t][r0 + 4], st[t][r0 + 5]);
        unsigned b1 = cvt_pk_bf16(st[t][r0 + 6], st[t][r0 + 7]);
        asm volatile("v_permlane32_swap_b32 %0, %1" : "+v"(b0), "+v"(a0));
        asm volatile("v_permlane32_swap_b32 %0, %1" : "+v"(b1), "+v"(a1));
        union { bf8_t v; unsigned u[4]; } pf;
        pf.u[0] = a0; pf.u[1] = a1; pf.u[2] = b0; pf.u[3] = b1;
        acc = mfma32(vf[t][kh], pf.v, acc);
      }
    }
  }
  // normalize and store O (B,H,T,D); row d = (reg&3)+8*(reg>>2)+4*hh
  float inv = 1.0f / lsum;
  size_t obase = ((size_t)bh * NT + q0 + lr) * ND + 4 * hh;
  #pragma unroll
  for (int c = 0; c < 4; ++c) {
    u32x2 o;
    o[0] = cvt_pk_bf16(acc[4 * c + 0] * inv, acc[4 * c + 1] * inv);
    o[1] = cvt_pk_bf16(acc[4 * c + 2] * inv, acc[4 * c + 3] * inv);
    *(u32x2*)(Ow + obase + 8 * c) = o;
  }
}

// ---------------------------------------------------------------------------
// Kernel 4: output projection Wp @ O + bp, times mask, f32 into d_out.
// (R2-proven M=64 x N=128 form, grid (8,32).)
// ---------------------------------------------------------------------------
__global__ __launch_bounds__(256) void outproj_kernel(
    const u16* __restrict__ Wc, const u16* __restrict__ Ow,
    const float* __restrict__ bp, float* __restrict__ out,
    const float* __restrict__ maskf) {
  const u16* W = Wc + (size_t)3 * NC * NC;
  int tid = threadIdx.x, wid = tid >> 6, lane = tid & 63;
  int lq = lane & 15, g = lane >> 4;
  int om0 = blockIdx.x * 64;
  int b   = blockIdx.y >> 4;
  int t0  = (blockIdx.y & 15) * 128 + wid * 32;
  const u16* Ob = Ow + (size_t)b * NH * NT * ND;

  const f32x4 zero = {0.f, 0.f, 0.f, 0.f};
  f32x4 acc[4][2];
  #pragma unroll
  for (int mt = 0; mt < 4; ++mt)
    #pragma unroll
    for (int nt = 0; nt < 2; ++nt) acc[mt][nt] = zero;

  for (int ks = 0; ks < 16; ++ks) {       // ks == head index; d-block = 8g
    bf8_t af[4], bfr[2];
    #pragma unroll
    for (int mt = 0; mt < 4; ++mt)
      af[mt] = *(const bf8_t*)(W + (size_t)(om0 + mt * 16 + lq) * NC + ks * 32 + 8 * g);
    #pragma unroll
    for (int nt = 0; nt < 2; ++nt)
      bfr[nt] = *(const bf8_t*)(Ob + ((size_t)ks * NT + t0 + nt * 16 + lq) * ND + 8 * g);
    #pragma unroll
    for (int mt = 0; mt < 4; ++mt)
      #pragma unroll
      for (int nt = 0; nt < 2; ++nt)
        acc[mt][nt] = mfma16(af[mt], bfr[nt], acc[mt][nt]);
  }
  #pragma unroll
  for (int mt = 0; mt < 4; ++mt) {
    int ob = om0 + mt * 16 + 4 * g;
    float b4[4];
    #pragma unroll
    for (int r = 0; r < 4; ++r) b4[r] = bp[ob + r];
    #pragma unroll
    for (int nt = 0; nt < 2; ++nt) {
      int t = t0 + nt * 16 + lq;
      float mv = maskf[b * NT + t];
      #pragma unroll
      for (int r = 0; r < 4; ++r)
        out[(size_t)(b * NC + ob + r) * NT + t] = (acc[mt][nt][r] + b4[r]) * mv;
    }
  }
}

// ---------------------------------------------------------------------------
extern "C" void kernel_launch(void* const* d_in, const int* in_sizes, int n_in,
                              void* d_out, int out_size, void* d_ws, size_t ws_size,
                              hipStream_t stream) {
  const float* q  = (const float*)d_in[0];
  const float* k  = (const float*)d_in[1];
  const float* v  = (const float*)d_in[2];
  const void*  mr = d_in[3];
  const float* Wq = (const float*)d_in[4];
  const float* bq = (const float*)d_in[5];
  const float* Wk = (const float*)d_in[6];
  const float* bk = (const float*)d_in[7];
  const float* Wv = (const float*)d_in[8];
  const float* bv = (const float*)d_in[9];
  const float* Wp = (const float*)d_in[10];
  const float* bp = (const float*)d_in[11];
  float* out = (float*)d_out;

  // workspace layout (~30 MB)
  u16* Wc = (u16*)d_ws;                                   // 4 * 512*512 bf16
  u16* Xt = Wc + (size_t)4 * NC * NC;                     // 3 * B*T*C bf16
  u16* Qw = Xt + (size_t)3 * NB * NT * NC;                // (B,H,T,D) bf16
  u16* Kw = Qw + (size_t)NB * NT * NC;
  u16* Vw = Kw + (size_t)NB * NT * NC;                    // (B,C,T)
  u16* Ow = Vw + (size_t)NB * NT * NC;                    // (B,H,T,D)
  float* maskf   = (float*)(Ow + (size_t)NB * NT * NC);   // B*T floats
  float* maskb   = maskf + (size_t)NB * NT;               // B*T floats (bias)
  float* outtail = out + (size_t)NB * NC * NT;            // mask chunk of d_out

  prep_kernel<<<dim3(64, 16, 7), dim3(32, 8), 0, stream>>>(
      q, k, v, Xt, Wq, Wk, Wv, Wp, mr, Wc, maskf, maskb, outtail);
  proj_kernel<<<dim3(8, 32, 3), 256, 0, stream>>>(Wc, Xt, bq, bk, bv, Qw, Kw, Vw, maskf);
  attn_kernel<<<dim3(16, 32), 256, 0, stream>>>(Qw, Kw, Vw, Ow, maskb);
  outproj_kernel<<<dim3(8, 32), 256, 0, stream>>>(Wc, Ow, bp, out, maskf);
}